// Round 16
// baseline (120.622 us; speedup 1.0000x reference)
//
#include <hip/hip_runtime.h>
#include <hip/hip_bf16.h>

typedef __attribute__((ext_vector_type(8))) short short8;
typedef __attribute__((ext_vector_type(4))) float float4v;
typedef __attribute__((address_space(3))) unsigned int as3u32;
typedef __attribute__((address_space(1))) unsigned int as1u32;

#define DIN 128
#define SSIZE 1024
#define MLGK 256
#define DOUT 10
#define TM 32    // x-rows per block; 2 waves x 16 rows
#define TS 32    // anchors per staged tile
#define NT 16    // anchor tiles PER HALF (512 anchors per block)
#define NTHR 128

union pk8 { unsigned int w[4]; short8 s8; };

#if __has_builtin(__builtin_amdgcn_sqrtf)
#define fsqrt_fast __builtin_amdgcn_sqrtf
#else
#define fsqrt_fast sqrtf
#endif

__device__ inline unsigned short f2bf(float f) {  // RNE
  unsigned int u = __float_as_uint(f);
  u = (u + 0x7FFFu + ((u >> 16) & 1u)) >> 16;
  return (unsigned short)u;
}
__device__ inline float bf2f(unsigned short h) {
  return __uint_as_float(((unsigned int)h) << 16);
}
__device__ inline unsigned int pkbf(float lo, float hi) {
  __hip_bfloat162 p = __float22bfloat162_rn(make_float2(lo, hi));
  unsigned int r;
  __builtin_memcpy(&r, &p, 4);
  return r;
}
__device__ inline float mish_f(float x) {
  if (x > 30.f) return x;
  float e = __expf(x);
  float u = 1.f + e;
  float u2 = u * u;
  return x * (u2 - 1.f) / (u2 + 1.f);
}
__device__ inline int swz(int row, int col) {
  return row * DIN + (col ^ ((row & 7) << 3));
}

// Stage a 32x128 bf16 tile into an 8KB LDS region via global_load_lds w=16,
// 128 threads. LDS dest LINEAR (rule #21); XOR swizzle on the GLOBAL source.
__device__ inline void stage8k(const unsigned short* __restrict__ gsrc,
                               unsigned short* region, int tid) {
#pragma unroll
  for (int it = 0; it < 4; ++it) {
    int slot = it * NTHR + tid;      // 0..511
    int r = slot >> 4;               // 0..31
    int c8 = (slot & 15) ^ (r & 7);
    __builtin_amdgcn_global_load_lds((const as1u32*)(gsrc + r * DIN + c8 * 8),
                                     (as3u32*)(region + slot * 8), 16, 0, 0);
  }
}

// ---------- single fused precompute kernel (R15-proven) ----------

__global__ __launch_bounds__(256) void k_pre(
    const float* __restrict__ W1, const float* __restrict__ W2,
    const float* __restrict__ Wc, const float* __restrict__ Wa,
    const float* __restrict__ mlg, const float* __restrict__ b1,
    const float* __restrict__ b2,
    unsigned short* W1b, unsigned short* W2b, unsigned short* Wcb,
    unsigned short* ancb, float* a2) {
  const int blk = blockIdx.x;
  const int tid = threadIdx.x;
  if (blk < 192) {
    int i = blk * 256 + tid;  // 49152 total
    if (i < 16384) {
      W1b[i] = f2bf(W1[i]);
    } else if (i < 32768) {
      W2b[i - 16384] = f2bf(W2[i - 16384]);
    } else {
      int j = i - 32768;  // [16][1024] padded Wc (rows >= DOUT zero)
      int o = j >> 10;
      int s = j & 1023;
      Wcb[j] = (o < DOUT) ? f2bf(Wc[o * SSIZE + s]) : (unsigned short)0;
    }
    return;
  }
  __shared__ __align__(16) float AR[8][132];
  __shared__ __align__(16) float OUT[8][132];
  __shared__ __align__(16) float WC[32][132];
  const int s0 = (blk - 192) * 8;

  {
    const int d = tid & 127;
    const int sg = tid >> 7;
    float ac0 = 0.f, ac1 = 0.f, ac2 = 0.f, ac3 = 0.f;
    const float* wr = Wa + (size_t)(s0 + sg * 4) * MLGK;
    for (int k = 0; k < MLGK; ++k) {
      float m = mlg[k * DIN + d];
      ac0 = fmaf(wr[0 * MLGK + k], m, ac0);
      ac1 = fmaf(wr[1 * MLGK + k], m, ac1);
      ac2 = fmaf(wr[2 * MLGK + k], m, ac2);
      ac3 = fmaf(wr[3 * MLGK + k], m, ac3);
    }
    AR[sg * 4 + 0][d] = tanhf(ac0);
    AR[sg * 4 + 1][d] = tanhf(ac1);
    AR[sg * 4 + 2][d] = tanhf(ac2);
    AR[sg * 4 + 3][d] = tanhf(ac3);
  }
  __syncthreads();

  const int a = tid >> 5;
  const int c = tid & 31;
  float sqacc = 0.f;
#pragma unroll 1
  for (int layer = 0; layer < 2; ++layer) {
    const float* W = layer ? W2 : W1;
    const float* bias = layer ? b2 : b1;
#pragma unroll 1
    for (int ch = 0; ch < 4; ++ch) {
      for (int i = tid; i < 32 * 32; i += 256) {
        int cr = i >> 5;
        int g = i & 31;
        float4 v = *(const float4*)&W[(size_t)(ch * 32 + cr) * DIN + g * 4];
        *(float4*)&WC[cr][g * 4] = v;
      }
      __syncthreads();
      float acc = 0.f;
      const float* src = layer ? &OUT[a][0] : &AR[a][0];
#pragma unroll
      for (int g = 0; g < 32; ++g) {
        float4 av = *(const float4*)&src[g * 4];
        float4 wv = *(const float4*)&WC[c][g * 4];
        acc = fmaf(av.x, wv.x, acc);
        acc = fmaf(av.y, wv.y, acc);
        acc = fmaf(av.z, wv.z, acc);
        acc = fmaf(av.w, wv.w, acc);
      }
      int col = ch * 32 + c;
      float m = mish_f(acc + bias[col]);
      if (layer == 0) {
        OUT[a][col] = m;
      } else {
        unsigned short mb = f2bf(m);
        ancb[(size_t)(s0 + a) * DIN + col] = mb;
        float v = bf2f(mb);
        sqacc = fmaf(v, v, sqacc);
      }
      __syncthreads();
    }
  }
  sqacc += __shfl_xor(sqacc, 1);
  sqacc += __shfl_xor(sqacc, 2);
  sqacc += __shfl_xor(sqacc, 4);
  sqacc += __shfl_xor(sqacc, 8);
  sqacc += __shfl_xor(sqacc, 16);
  if (c == 0) a2[s0 + a] = sqacc;
}

// ---------- fused main kernel (R12 body, anchor-split across 2 halves) ----------
// grid 4096 = 2048 row-tiles x 2 anchor-halves; 16 blocks/CU scheduled,
// 10 resident (LDS 16KB) -> ~20 waves/CU (62% vs R12's 37%). Each block:
// encode 32 rows (duplicated per half, cheap) + dist over its 512 anchors
// (16 tiles of 32) -> PARTIAL logits to P[half][row][16] f32 (disjoint
// writes, deterministic). k_post sums halves + bias + log_softmax.

__global__ __launch_bounds__(NTHR, 8) void k_main(
    const float* __restrict__ x, const float* __restrict__ b1,
    const float* __restrict__ b2,
    const unsigned short* __restrict__ W1b, const unsigned short* __restrict__ W2b,
    const unsigned short* __restrict__ Wcb, const unsigned short* __restrict__ ancb,
    const float* __restrict__ a2, float* __restrict__ P) {
  __shared__ __align__(16) unsigned short reg0[TM * DIN];
  __shared__ __align__(16) unsigned short reg1[TM * DIN];

  const int tid = threadIdx.x;
  const int lane = tid & 63;
  const int l15 = lane & 15;
  const int lhi = lane >> 4;
  const int rt = blockIdx.x & 2047;
  const int half = blockIdx.x >> 11;
  const int n0 = rt * TM;
  const int rbase = (tid >> 6) * 16;

  stage8k(W1b, reg1, tid);

  // ---- x rows -> bf16 A-fragments ----
  short8 af[4];
#pragma unroll
  for (int kk = 0; kk < 4; ++kk) {
    const float* p = x + (size_t)(n0 + rbase + l15) * DIN + kk * 32 + lhi * 8;
    float4 u = *(const float4*)p;
    float4 v = *(const float4*)(p + 4);
    pk8 a;
    a.w[0] = pkbf(u.x, u.y);
    a.w[1] = pkbf(u.z, u.w);
    a.w[2] = pkbf(v.x, v.y);
    a.w[3] = pkbf(v.z, v.w);
    af[kk] = a.s8;
  }

  // ---- encode: 2 layers x 4 staged 32-col quarters of W ----
  short8 ah[4];
#pragma unroll
  for (int kk = 0; kk < 4; ++kk) ah[kk] = af[kk];
#pragma unroll 1
  for (int qq = 0; qq < 8; ++qq) {
    const int layer = qq >> 2;
    const int q = qq & 3;
    const float* bias = layer ? b2 : b1;
    if (q == 0 && layer == 1) {
#pragma unroll
      for (int kk = 0; kk < 4; ++kk)
        ah[kk] = *(const short8*)&reg0[swz(rbase + l15, kk * 32 + lhi * 8)];
    }
    __syncthreads();
    float4v acc0 = (float4v){0.f, 0.f, 0.f, 0.f};
    float4v acc1 = (float4v){0.f, 0.f, 0.f, 0.f};
#pragma unroll
    for (int kk = 0; kk < 4; ++kk) {
      int k = kk * 32 + lhi * 8;
      short8 bA = *(const short8*)&reg1[swz(l15, k)];
      short8 bB = *(const short8*)&reg1[swz(16 + l15, k)];
      acc0 = __builtin_amdgcn_mfma_f32_16x16x32_bf16(ah[kk], bA, acc0, 0, 0, 0);
      acc1 = __builtin_amdgcn_mfma_f32_16x16x32_bf16(ah[kk], bB, acc1, 0, 0, 0);
    }
    __syncthreads();
    if (qq < 7) {
      const unsigned short* Wn = (qq + 1 < 4) ? W1b + (size_t)((qq + 1) * 32) * DIN
                                              : W2b + (size_t)(((qq + 1) & 3) * 32) * DIN;
      stage8k(Wn, reg1, tid);
    }
#pragma unroll
    for (int ct = 0; ct < 2; ++ct) {
      float4v accv = ct ? acc1 : acc0;
      int col = q * 32 + ct * 16 + l15;
      float bv = bias[col];
      float m0 = mish_f(accv[0] + bv);
      float m1 = mish_f(accv[1] + bv);
      float m2 = mish_f(accv[2] + bv);
      float m3 = mish_f(accv[3] + bv);
      unsigned int w01 = pkbf(m0, m1);
      unsigned int w23 = pkbf(m2, m3);
      int r0 = rbase + lhi * 4;
      reg0[swz(r0 + 0, col)] = (unsigned short)(w01 & 0xffff);
      reg0[swz(r0 + 1, col)] = (unsigned short)(w01 >> 16);
      reg0[swz(r0 + 2, col)] = (unsigned short)(w23 & 0xffff);
      reg0[swz(r0 + 3, col)] = (unsigned short)(w23 >> 16);
    }
  }

  // ---- hoist x_dml B-fragments; row norm ----
  short8 bx[4];
#pragma unroll
  for (int kk = 0; kk < 4; ++kk)
    bx[kk] = *(const short8*)&reg0[swz(rbase + l15, kk * 32 + lhi * 8)];
  float x2v = 0.f;
#pragma unroll
  for (int kk = 0; kk < 4; ++kk)
#pragma unroll
    for (int e = 0; e < 8; ++e) {
      float v = bf2f((unsigned short)bx[kk][e]);
      x2v = fmaf(v, v, x2v);
    }
  x2v += __shfl_xor(x2v, 16);
  x2v += __shfl_xor(x2v, 32);

  // ---- this half's anchor views + tile-0 a2/Wc prefetch ----
  const unsigned short* ancH = ancb + (size_t)(half * 512) * DIN;
  const float* a2H = a2 + half * 512;
  const unsigned short* wcrow = Wcb + l15 * SSIZE + half * 512;
  float4 av0 = *(const float4*)(a2H + lhi * 4);
  float4 av1 = *(const float4*)(a2H + 16 + lhi * 4);
  uint2 wv0 = *(const uint2*)(wcrow + lhi * 4);
  uint2 wv1 = *(const uint2*)(wcrow + 16 + lhi * 4);
  __syncthreads();

  // ---- distance + in-register partial logits over 16 anchor tiles ----
  float4v lacc = (float4v){0.f, 0.f, 0.f, 0.f};

  auto dist_tile = [&](const unsigned short* buf, int t) {
    int tn = (t + 1) & (NT - 1);
    const float* a2n = a2H + tn * TS + lhi * 4;
    const unsigned short* wcn = wcrow + tn * TS + lhi * 4;
    float4 an0 = *(const float4*)(a2n + 0);
    float4 an1 = *(const float4*)(a2n + 16);
    uint2 wn0 = *(const uint2*)(wcn + 0);
    uint2 wn1 = *(const uint2*)(wcn + 16);

    float4v acc0 = (float4v){0.f, 0.f, 0.f, 0.f};
    float4v acc1 = (float4v){0.f, 0.f, 0.f, 0.f};
    __builtin_amdgcn_s_setprio(1);
#pragma unroll
    for (int kk = 0; kk < 4; ++kk) {
      int k = kk * 32 + lhi * 8;
      short8 aA = *(const short8*)&buf[swz(l15, k)];
      short8 aB = *(const short8*)&buf[swz(16 + l15, k)];
      acc0 = __builtin_amdgcn_mfma_f32_16x16x32_bf16(aA, bx[kk], acc0, 0, 0, 0);
      acc1 = __builtin_amdgcn_mfma_f32_16x16x32_bf16(aB, bx[kk], acc1, 0, 0, 0);
    }
    __builtin_amdgcn_s_setprio(0);
    {
      pk8 A, B;
      float d0 = fsqrt_fast(fmaxf(fmaf(-2.f, acc0[0], x2v + av0.x), 0.f));
      float d1 = fsqrt_fast(fmaxf(fmaf(-2.f, acc0[1], x2v + av0.y), 0.f));
      float d2 = fsqrt_fast(fmaxf(fmaf(-2.f, acc0[2], x2v + av0.z), 0.f));
      float d3 = fsqrt_fast(fmaxf(fmaf(-2.f, acc0[3], x2v + av0.w), 0.f));
      A.w[0] = wv0.x; A.w[1] = wv0.y;
      B.w[0] = pkbf(d0, d1); B.w[1] = pkbf(d2, d3);
      float e0 = fsqrt_fast(fmaxf(fmaf(-2.f, acc1[0], x2v + av1.x), 0.f));
      float e1 = fsqrt_fast(fmaxf(fmaf(-2.f, acc1[1], x2v + av1.y), 0.f));
      float e2 = fsqrt_fast(fmaxf(fmaf(-2.f, acc1[2], x2v + av1.z), 0.f));
      float e3 = fsqrt_fast(fmaxf(fmaf(-2.f, acc1[3], x2v + av1.w), 0.f));
      A.w[2] = wv1.x; A.w[3] = wv1.y;
      B.w[2] = pkbf(e0, e1); B.w[3] = pkbf(e2, e3);
      lacc = __builtin_amdgcn_mfma_f32_16x16x32_bf16(A.s8, B.s8, lacc, 0, 0, 0);
    }
    av0 = an0; av1 = an1; wv0 = wn0; wv1 = wn1;
  };

  stage8k(ancH, reg0, tid);  // tile 0
  __syncthreads();
#pragma unroll 1
  for (int tp = 0; tp < NT / 2; ++tp) {
    stage8k(ancH + (size_t)(2 * tp + 1) * TS * DIN, reg1, tid);
    dist_tile(reg0, 2 * tp);
    __syncthreads();
    if (tp < NT / 2 - 1)
      stage8k(ancH + (size_t)(2 * tp + 2) * TS * DIN, reg0, tid);
    dist_tile(reg1, 2 * tp + 1);
    __syncthreads();
  }

  // ---- write partial logits (disjoint per half; o in [0,16)) ----
  {
    const int xrow = n0 + rbase + l15;
    float* pr = P + ((size_t)half << 20) + (size_t)xrow * 16 + lhi * 4;
    pr[0] = lacc[0];
    pr[1] = lacc[1];
    pr[2] = lacc[2];
    pr[3] = lacc[3];
  }
}

// ---------- epilogue: sum halves + bias + log_softmax ----------
__global__ __launch_bounds__(256) void k_post(const float* __restrict__ P,
                                              const float* __restrict__ bc,
                                              float* __restrict__ out) {
  int r = blockIdx.x * 256 + threadIdx.x;  // 65536 rows
  const float* p0 = P + (size_t)r * 16;
  const float* p1 = P + (1u << 20) + (size_t)r * 16;
  float v[DOUT];
  float m = -1e30f;
#pragma unroll
  for (int o = 0; o < DOUT; ++o) {
    v[o] = p0[o] + p1[o] + bc[o];
    m = fmaxf(m, v[o]);
  }
  float es = 0.f;
#pragma unroll
  for (int o = 0; o < DOUT; ++o) es += __expf(v[o] - m);
  float ls = logf(es);
#pragma unroll
  for (int o = 0; o < DOUT; ++o) out[(size_t)r * DOUT + o] = v[o] - m - ls;
}

extern "C" void kernel_launch(void* const* d_in, const int* in_sizes, int n_in,
                              void* d_out, int out_size, void* d_ws, size_t ws_size,
                              hipStream_t stream) {
  const float* x   = (const float*)d_in[0];
  const float* mlg = (const float*)d_in[1];
  const float* W1  = (const float*)d_in[2];
  const float* b1  = (const float*)d_in[3];
  const float* W2  = (const float*)d_in[4];
  const float* b2  = (const float*)d_in[5];
  const float* Wa  = (const float*)d_in[6];
  const float* Wc  = (const float*)d_in[7];
  const float* bc  = (const float*)d_in[8];
  float* out = (float*)d_out;

  // workspace layout: ~0.36 MB tables + 8.4 MB partial-logits buffer
  unsigned short* W1b  = (unsigned short*)d_ws;        // 16384 bf16
  unsigned short* W2b  = W1b + 16384;                  // 16384 bf16
  unsigned short* Wcb  = W2b + 16384;                  // 16*1024 bf16 (zero-padded)
  unsigned short* ancb = Wcb + 16384;                  // 1024*128 bf16
  float* a2 = (float*)(ancb + SSIZE * DIN);            // 1024 f32
  float* P  = a2 + SSIZE;                              // 2 x 65536 x 16 f32

  k_pre<<<320, 256, 0, stream>>>(W1, W2, Wc, Wa, mlg, b1, b2,
                                 W1b, W2b, Wcb, ancb, a2);
  k_main<<<4096, NTHR, 0, stream>>>(x, b1, b2, W1b, W2b, Wcb, ancb, a2, P);
  k_post<<<256, 256, 0, stream>>>(P, bc, out);
}

// Round 17
// 86.172 us; speedup vs baseline: 1.3998x; 1.3998x over previous
//
#include <hip/hip_runtime.h>
#include <hip/hip_bf16.h>

typedef __attribute__((ext_vector_type(8))) short short8;
typedef __attribute__((ext_vector_type(4))) float float4v;
typedef __attribute__((address_space(3))) unsigned int as3u32;
typedef __attribute__((address_space(1))) unsigned int as1u32;

#define DIN 128
#define SSIZE 1024
#define MLGK 256
#define DOUT 10
#define TM 64    // x-rows per block; 2 waves x 32 rows (2 halves of 16)
#define TS 32    // anchors per staged tile
#define NT 32    // anchor tiles
#define NTHR 128

union pk8 { unsigned int w[4]; short8 s8; };

#if __has_builtin(__builtin_amdgcn_sqrtf)
#define fsqrt_fast __builtin_amdgcn_sqrtf
#else
#define fsqrt_fast sqrtf
#endif

__device__ inline unsigned short f2bf(float f) {  // RNE
  unsigned int u = __float_as_uint(f);
  u = (u + 0x7FFFu + ((u >> 16) & 1u)) >> 16;
  return (unsigned short)u;
}
__device__ inline float bf2f(unsigned short h) {
  return __uint_as_float(((unsigned int)h) << 16);
}
__device__ inline unsigned int pkbf(float lo, float hi) {
  __hip_bfloat162 p = __float22bfloat162_rn(make_float2(lo, hi));
  unsigned int r;
  __builtin_memcpy(&r, &p, 4);
  return r;
}
__device__ inline float mish_f(float x) {
  if (x > 30.f) return x;
  float e = __expf(x);
  float u = 1.f + e;
  float u2 = u * u;
  return x * (u2 - 1.f) / (u2 + 1.f);
}
__device__ inline int swz(int row, int col) {
  return row * DIN + (col ^ ((row & 7) << 3));
}

// Stage a 32x128 bf16 tile into an 8KB LDS region via global_load_lds w=16,
// 128 threads. LDS dest LINEAR (rule #21); XOR swizzle on the GLOBAL source.
__device__ inline void stage8k(const unsigned short* __restrict__ gsrc,
                               unsigned short* region, int tid) {
#pragma unroll
  for (int it = 0; it < 4; ++it) {
    int slot = it * NTHR + tid;      // 0..511
    int r = slot >> 4;               // 0..31
    int c8 = (slot & 15) ^ (r & 7);
    __builtin_amdgcn_global_load_lds((const as1u32*)(gsrc + r * DIN + c8 * 8),
                                     (as3u32*)(region + slot * 8), 16, 0, 0);
  }
}

// ---------- single fused precompute kernel (R15-proven) ----------

__global__ __launch_bounds__(256) void k_pre(
    const float* __restrict__ W1, const float* __restrict__ W2,
    const float* __restrict__ Wc, const float* __restrict__ Wa,
    const float* __restrict__ mlg, const float* __restrict__ b1,
    const float* __restrict__ b2,
    unsigned short* W1b, unsigned short* W2b, unsigned short* Wcb,
    unsigned short* ancb, float* a2) {
  const int blk = blockIdx.x;
  const int tid = threadIdx.x;
  if (blk < 192) {
    int i = blk * 256 + tid;  // 49152 total
    if (i < 16384) {
      W1b[i] = f2bf(W1[i]);
    } else if (i < 32768) {
      W2b[i - 16384] = f2bf(W2[i - 16384]);
    } else {
      int j = i - 32768;  // [16][1024] padded Wc (rows >= DOUT zero)
      int o = j >> 10;
      int s = j & 1023;
      Wcb[j] = (o < DOUT) ? f2bf(Wc[o * SSIZE + s]) : (unsigned short)0;
    }
    return;
  }
  __shared__ __align__(16) float AR[8][132];
  __shared__ __align__(16) float OUT[8][132];
  __shared__ __align__(16) float WC[32][132];
  const int s0 = (blk - 192) * 8;

  {
    const int d = tid & 127;
    const int sg = tid >> 7;
    float ac0 = 0.f, ac1 = 0.f, ac2 = 0.f, ac3 = 0.f;
    const float* wr = Wa + (size_t)(s0 + sg * 4) * MLGK;
    for (int k = 0; k < MLGK; ++k) {
      float m = mlg[k * DIN + d];
      ac0 = fmaf(wr[0 * MLGK + k], m, ac0);
      ac1 = fmaf(wr[1 * MLGK + k], m, ac1);
      ac2 = fmaf(wr[2 * MLGK + k], m, ac2);
      ac3 = fmaf(wr[3 * MLGK + k], m, ac3);
    }
    AR[sg * 4 + 0][d] = tanhf(ac0);
    AR[sg * 4 + 1][d] = tanhf(ac1);
    AR[sg * 4 + 2][d] = tanhf(ac2);
    AR[sg * 4 + 3][d] = tanhf(ac3);
  }
  __syncthreads();

  const int a = tid >> 5;
  const int c = tid & 31;
  float sqacc = 0.f;
#pragma unroll 1
  for (int layer = 0; layer < 2; ++layer) {
    const float* W = layer ? W2 : W1;
    const float* bias = layer ? b2 : b1;
#pragma unroll 1
    for (int ch = 0; ch < 4; ++ch) {
      for (int i = tid; i < 32 * 32; i += 256) {
        int cr = i >> 5;
        int g = i & 31;
        float4 v = *(const float4*)&W[(size_t)(ch * 32 + cr) * DIN + g * 4];
        *(float4*)&WC[cr][g * 4] = v;
      }
      __syncthreads();
      float acc = 0.f;
      const float* src = layer ? &OUT[a][0] : &AR[a][0];
#pragma unroll
      for (int g = 0; g < 32; ++g) {
        float4 av = *(const float4*)&src[g * 4];
        float4 wv = *(const float4*)&WC[c][g * 4];
        acc = fmaf(av.x, wv.x, acc);
        acc = fmaf(av.y, wv.y, acc);
        acc = fmaf(av.z, wv.z, acc);
        acc = fmaf(av.w, wv.w, acc);
      }
      int col = ch * 32 + c;
      float m = mish_f(acc + bias[col]);
      if (layer == 0) {
        OUT[a][col] = m;
      } else {
        unsigned short mb = f2bf(m);
        ancb[(size_t)(s0 + a) * DIN + col] = mb;
        float v = bf2f(mb);
        sqacc = fmaf(v, v, sqacc);
      }
      __syncthreads();
    }
  }
  sqacc += __shfl_xor(sqacc, 1);
  sqacc += __shfl_xor(sqacc, 2);
  sqacc += __shfl_xor(sqacc, 4);
  sqacc += __shfl_xor(sqacc, 8);
  sqacc += __shfl_xor(sqacc, 16);
  if (c == 0) a2[s0 + a] = sqacc;
}

// ---------- fused main kernel: TM=64, 2 waves x 32 rows ----------
// Halves per-wave LDS reads + stage traffic vs R12 (each staged anchor tile
// serves 64 rows; ds:MFMA = 1:2.25). LDS 24KB -> 6 blocks x 2 waves = 12
// waves/CU (same residency as R12's measured cap). Encode/dist skeleton =
// R12; dual-half epilogue = R14 (both proven, absmax 0.125).

__global__ __launch_bounds__(NTHR, 3) void k_main(
    const float* __restrict__ x, const float* __restrict__ b1,
    const float* __restrict__ b2, const float* __restrict__ bc,
    const unsigned short* __restrict__ W1b, const unsigned short* __restrict__ W2b,
    const unsigned short* __restrict__ Wcb, const unsigned short* __restrict__ ancb,
    const float* __restrict__ a2, float* __restrict__ out) {
  __shared__ __align__(16) unsigned short reg0[TM * DIN];  // x_dml; anchor buf A (first 8KB)
  __shared__ __align__(16) unsigned short reg1[TS * DIN];  // W quarters; anchor buf B

  const int tid = threadIdx.x;
  const int lane = tid & 63;
  const int l15 = lane & 15;
  const int lhi = lane >> 4;
  const int n0 = blockIdx.x * TM;
  const int wbase = (tid >> 6) * 32;   // wave 0 -> rows 0-31, wave 1 -> 32-63

  // issue first W quarter stage; x loads fly underneath
  stage8k(W1b, reg1, tid);

  // ---- x rows -> bf16 A-fragments (2 halves) ----
  short8 ah0[4], ah1[4];
#pragma unroll
  for (int h = 0; h < 2; ++h) {
#pragma unroll
    for (int kk = 0; kk < 4; ++kk) {
      const float* p = x + (size_t)(n0 + wbase + h * 16 + l15) * DIN + kk * 32 + lhi * 8;
      float4 u = *(const float4*)p;
      float4 v = *(const float4*)(p + 4);
      pk8 a;
      a.w[0] = pkbf(u.x, u.y);
      a.w[1] = pkbf(u.z, u.w);
      a.w[2] = pkbf(v.x, v.y);
      a.w[3] = pkbf(v.z, v.w);
      if (h == 0) ah0[kk] = a.s8; else ah1[kk] = a.s8;
    }
  }

  // ---- encode: 2 layers x 4 staged 32-col quarters of W ----
#pragma unroll 1
  for (int qq = 0; qq < 8; ++qq) {
    const int layer = qq >> 2;
    const int q = qq & 3;
    const float* bias = layer ? b2 : b1;
    if (q == 0 && layer == 1) {
      // reload A-fragments from h (own rows; wave-private, lgkmcnt-ordered)
#pragma unroll
      for (int kk = 0; kk < 4; ++kk) {
        ah0[kk] = *(const short8*)&reg0[swz(wbase + l15, kk * 32 + lhi * 8)];
        ah1[kk] = *(const short8*)&reg0[swz(wbase + 16 + l15, kk * 32 + lhi * 8)];
      }
    }
    __syncthreads();  // quarter qq staged (vmcnt drained by barrier)
    float4v e00 = (float4v){0.f, 0.f, 0.f, 0.f};  // (half0, ct0)
    float4v e10 = (float4v){0.f, 0.f, 0.f, 0.f};  // (half0, ct1)
    float4v e01 = (float4v){0.f, 0.f, 0.f, 0.f};  // (half1, ct0)
    float4v e11 = (float4v){0.f, 0.f, 0.f, 0.f};  // (half1, ct1)
#pragma unroll
    for (int kk = 0; kk < 4; ++kk) {
      int k = kk * 32 + lhi * 8;
      short8 w0 = *(const short8*)&reg1[swz(l15, k)];
      short8 w1 = *(const short8*)&reg1[swz(16 + l15, k)];
      e00 = __builtin_amdgcn_mfma_f32_16x16x32_bf16(ah0[kk], w0, e00, 0, 0, 0);
      e10 = __builtin_amdgcn_mfma_f32_16x16x32_bf16(ah0[kk], w1, e10, 0, 0, 0);
      e01 = __builtin_amdgcn_mfma_f32_16x16x32_bf16(ah1[kk], w0, e01, 0, 0, 0);
      e11 = __builtin_amdgcn_mfma_f32_16x16x32_bf16(ah1[kk], w1, e11, 0, 0, 0);
    }
    __syncthreads();  // all waves done reading reg1
    if (qq < 7) {
      const unsigned short* Wn = (qq + 1 < 4) ? W1b + (size_t)((qq + 1) * 32) * DIN
                                              : W2b + (size_t)(((qq + 1) & 3) * 32) * DIN;
      stage8k(Wn, reg1, tid);
    }
#pragma unroll
    for (int h = 0; h < 2; ++h) {
#pragma unroll
      for (int ct = 0; ct < 2; ++ct) {
        float4v accv = (h == 0) ? (ct ? e10 : e00) : (ct ? e11 : e01);
        int col = q * 32 + ct * 16 + l15;
        float bv = bias[col];
        float m0 = mish_f(accv[0] + bv);
        float m1 = mish_f(accv[1] + bv);
        float m2 = mish_f(accv[2] + bv);
        float m3 = mish_f(accv[3] + bv);
        unsigned int w01 = pkbf(m0, m1);
        unsigned int w23 = pkbf(m2, m3);
        int r0 = wbase + h * 16 + lhi * 4;
        reg0[swz(r0 + 0, col)] = (unsigned short)(w01 & 0xffff);
        reg0[swz(r0 + 1, col)] = (unsigned short)(w01 >> 16);
        reg0[swz(r0 + 2, col)] = (unsigned short)(w23 & 0xffff);
        reg0[swz(r0 + 3, col)] = (unsigned short)(w23 >> 16);
      }
    }
  }

  // ---- hoist x_dml B-fragments (both halves) + row norms ----
  short8 bx0[4], bx1[4];
#pragma unroll
  for (int kk = 0; kk < 4; ++kk) {
    bx0[kk] = *(const short8*)&reg0[swz(wbase + l15, kk * 32 + lhi * 8)];
    bx1[kk] = *(const short8*)&reg0[swz(wbase + 16 + l15, kk * 32 + lhi * 8)];
  }
  float x2v0 = 0.f, x2v1 = 0.f;
#pragma unroll
  for (int kk = 0; kk < 4; ++kk)
#pragma unroll
    for (int e = 0; e < 8; ++e) {
      float v0 = bf2f((unsigned short)bx0[kk][e]);
      float v1 = bf2f((unsigned short)bx1[kk][e]);
      x2v0 = fmaf(v0, v0, x2v0);
      x2v1 = fmaf(v1, v1, x2v1);
    }
  x2v0 += __shfl_xor(x2v0, 16); x2v0 += __shfl_xor(x2v0, 32);
  x2v1 += __shfl_xor(x2v1, 16); x2v1 += __shfl_xor(x2v1, 32);

  // ---- prefetch tile 0's a2 / Wc (named scalars, shared by both halves) ----
  const unsigned short* wcrow = Wcb + l15 * SSIZE;
  float4 av0 = *(const float4*)(a2 + lhi * 4);
  float4 av1 = *(const float4*)(a2 + 16 + lhi * 4);
  uint2 wv0 = *(const uint2*)(wcrow + lhi * 4);
  uint2 wv1 = *(const uint2*)(wcrow + 16 + lhi * 4);
  __syncthreads();              // everyone hoisted before anchor staging

  // ---- distance + in-register logits over 32 anchor tiles of 32 ----
  float4v lacc0 = (float4v){0.f, 0.f, 0.f, 0.f};
  float4v lacc1 = (float4v){0.f, 0.f, 0.f, 0.f};

  auto dist_tile = [&](const unsigned short* buf, int t) {
    int tn = (t + 1) & (NT - 1);
    const float* a2n = a2 + tn * TS + lhi * 4;
    const unsigned short* wcn = wcrow + tn * TS + lhi * 4;
    float4 an0 = *(const float4*)(a2n + 0);
    float4 an1 = *(const float4*)(a2n + 16);
    uint2 wn0 = *(const uint2*)(wcn + 0);
    uint2 wn1 = *(const uint2*)(wcn + 16);

    float4v a00 = (float4v){0.f, 0.f, 0.f, 0.f};  // (ct0, half0)
    float4v a01 = (float4v){0.f, 0.f, 0.f, 0.f};  // (ct0, half1)
    float4v a10 = (float4v){0.f, 0.f, 0.f, 0.f};  // (ct1, half0)
    float4v a11 = (float4v){0.f, 0.f, 0.f, 0.f};  // (ct1, half1)
    __builtin_amdgcn_s_setprio(1);
#pragma unroll
    for (int kk = 0; kk < 4; ++kk) {
      int k = kk * 32 + lhi * 8;
      short8 f0 = *(const short8*)&buf[swz(l15, k)];       // anchors ct0
      short8 f1 = *(const short8*)&buf[swz(16 + l15, k)];  // anchors ct1
      a00 = __builtin_amdgcn_mfma_f32_16x16x32_bf16(f0, bx0[kk], a00, 0, 0, 0);
      a01 = __builtin_amdgcn_mfma_f32_16x16x32_bf16(f0, bx1[kk], a01, 0, 0, 0);
      a10 = __builtin_amdgcn_mfma_f32_16x16x32_bf16(f1, bx0[kk], a10, 0, 0, 0);
      a11 = __builtin_amdgcn_mfma_f32_16x16x32_bf16(f1, bx1[kk], a11, 0, 0, 0);
    }
    __builtin_amdgcn_s_setprio(0);
    // epilogue half 0 (rows wbase+l15)
    {
      pk8 A, B;
      float d0 = fsqrt_fast(fmaxf(fmaf(-2.f, a00[0], x2v0 + av0.x), 0.f));
      float d1 = fsqrt_fast(fmaxf(fmaf(-2.f, a00[1], x2v0 + av0.y), 0.f));
      float d2 = fsqrt_fast(fmaxf(fmaf(-2.f, a00[2], x2v0 + av0.z), 0.f));
      float d3 = fsqrt_fast(fmaxf(fmaf(-2.f, a00[3], x2v0 + av0.w), 0.f));
      A.w[0] = wv0.x; A.w[1] = wv0.y;
      B.w[0] = pkbf(d0, d1); B.w[1] = pkbf(d2, d3);
      float e0 = fsqrt_fast(fmaxf(fmaf(-2.f, a10[0], x2v0 + av1.x), 0.f));
      float e1 = fsqrt_fast(fmaxf(fmaf(-2.f, a10[1], x2v0 + av1.y), 0.f));
      float e2 = fsqrt_fast(fmaxf(fmaf(-2.f, a10[2], x2v0 + av1.z), 0.f));
      float e3 = fsqrt_fast(fmaxf(fmaf(-2.f, a10[3], x2v0 + av1.w), 0.f));
      A.w[2] = wv1.x; A.w[3] = wv1.y;
      B.w[2] = pkbf(e0, e1); B.w[3] = pkbf(e2, e3);
      lacc0 = __builtin_amdgcn_mfma_f32_16x16x32_bf16(A.s8, B.s8, lacc0, 0, 0, 0);
    }
    // epilogue half 1 (rows wbase+16+l15)
    {
      pk8 A, B;
      float d0 = fsqrt_fast(fmaxf(fmaf(-2.f, a01[0], x2v1 + av0.x), 0.f));
      float d1 = fsqrt_fast(fmaxf(fmaf(-2.f, a01[1], x2v1 + av0.y), 0.f));
      float d2 = fsqrt_fast(fmaxf(fmaf(-2.f, a01[2], x2v1 + av0.z), 0.f));
      float d3 = fsqrt_fast(fmaxf(fmaf(-2.f, a01[3], x2v1 + av0.w), 0.f));
      A.w[0] = wv0.x; A.w[1] = wv0.y;
      B.w[0] = pkbf(d0, d1); B.w[1] = pkbf(d2, d3);
      float e0 = fsqrt_fast(fmaxf(fmaf(-2.f, a11[0], x2v1 + av1.x), 0.f));
      float e1 = fsqrt_fast(fmaxf(fmaf(-2.f, a11[1], x2v1 + av1.y), 0.f));
      float e2 = fsqrt_fast(fmaxf(fmaf(-2.f, a11[2], x2v1 + av1.z), 0.f));
      float e3 = fsqrt_fast(fmaxf(fmaf(-2.f, a11[3], x2v1 + av1.w), 0.f));
      A.w[2] = wv1.x; A.w[3] = wv1.y;
      B.w[2] = pkbf(e0, e1); B.w[3] = pkbf(e2, e3);
      lacc1 = __builtin_amdgcn_mfma_f32_16x16x32_bf16(A.s8, B.s8, lacc1, 0, 0, 0);
    }
    av0 = an0; av1 = an1; wv0 = wn0; wv1 = wn1;
  };

  stage8k(ancb, reg0, tid);  // tile 0 -> buf A (first 8KB of reg0)
  __syncthreads();
#pragma unroll 1
  for (int tp = 0; tp < NT / 2; ++tp) {
    stage8k(ancb + (size_t)(2 * tp + 1) * TS * DIN, reg1, tid);
    dist_tile(reg0, 2 * tp);
    __syncthreads();
    if (tp < NT / 2 - 1)
      stage8k(ancb + (size_t)(2 * tp + 2) * TS * DIN, reg0, tid);
    dist_tile(reg1, 2 * tp + 1);
    __syncthreads();
  }

  // ---- bias + log_softmax + store, per row-half ----
#pragma unroll
  for (int h = 0; h < 2; ++h) {
    float4v L = h ? lacc1 : lacc0;
    const int xrow = n0 + wbase + h * 16 + l15;
    float v[4];
    float m4 = -1e30f;
#pragma unroll
    for (int j = 0; j < 4; ++j) {
      int o = lhi * 4 + j;
      v[j] = (o < DOUT) ? (L[j] + bc[o]) : -1e30f;
      m4 = fmaxf(m4, v[j]);
    }
    m4 = fmaxf(m4, __shfl_xor(m4, 16));
    m4 = fmaxf(m4, __shfl_xor(m4, 32));
    float es = 0.f;
#pragma unroll
    for (int j = 0; j < 4; ++j) {
      int o = lhi * 4 + j;
      es += (o < DOUT) ? __expf(v[j] - m4) : 0.f;
    }
    es += __shfl_xor(es, 16);
    es += __shfl_xor(es, 32);
    float ls = logf(es);
#pragma unroll
    for (int j = 0; j < 4; ++j) {
      int o = lhi * 4 + j;
      if (o < DOUT) out[(size_t)xrow * DOUT + o] = v[j] - m4 - ls;
    }
  }
}

extern "C" void kernel_launch(void* const* d_in, const int* in_sizes, int n_in,
                              void* d_out, int out_size, void* d_ws, size_t ws_size,
                              hipStream_t stream) {
  const float* x   = (const float*)d_in[0];
  const float* mlg = (const float*)d_in[1];
  const float* W1  = (const float*)d_in[2];
  const float* b1  = (const float*)d_in[3];
  const float* W2  = (const float*)d_in[4];
  const float* b2  = (const float*)d_in[5];
  const float* Wa  = (const float*)d_in[6];
  const float* Wc  = (const float*)d_in[7];
  const float* bc  = (const float*)d_in[8];
  float* out = (float*)d_out;

  // workspace layout (~0.36 MB)
  unsigned short* W1b  = (unsigned short*)d_ws;        // 16384 bf16
  unsigned short* W2b  = W1b + 16384;                  // 16384 bf16
  unsigned short* Wcb  = W2b + 16384;                  // 16*1024 bf16 (zero-padded)
  unsigned short* ancb = Wcb + 16384;                  // 1024*128 bf16
  float* a2 = (float*)(ancb + SSIZE * DIN);            // 1024 f32

  k_pre<<<320, 256, 0, stream>>>(W1, W2, Wc, Wa, mlg, b1, b2,
                                 W1b, W2b, Wcb, ancb, a2);
  k_main<<<1024, NTHR, 0, stream>>>(x, b1, b2, bc, W1b, W2b, Wcb, ancb, a2, out);
}

// Round 18
// 83.763 us; speedup vs baseline: 1.4400x; 1.0288x over previous
//
#include <hip/hip_runtime.h>
#include <hip/hip_bf16.h>

typedef __attribute__((ext_vector_type(8))) short short8;
typedef __attribute__((ext_vector_type(4))) float float4v;
typedef __attribute__((address_space(3))) unsigned int as3u32;
typedef __attribute__((address_space(1))) unsigned int as1u32;

#define DIN 128
#define SSIZE 1024
#define MLGK 256
#define DOUT 10
#define TM 128   // x-rows per block; 4 waves x 32 rows (2 halves of 16)
#define TS 32    // anchors per staged tile
#define NT 32    // anchor tiles
#define NTHR 256

union pk8 { unsigned int w[4]; short8 s8; };

#if __has_builtin(__builtin_amdgcn_sqrtf)
#define fsqrt_fast __builtin_amdgcn_sqrtf
#else
#define fsqrt_fast sqrtf
#endif

__device__ inline unsigned short f2bf(float f) {  // RNE
  unsigned int u = __float_as_uint(f);
  u = (u + 0x7FFFu + ((u >> 16) & 1u)) >> 16;
  return (unsigned short)u;
}
__device__ inline float bf2f(unsigned short h) {
  return __uint_as_float(((unsigned int)h) << 16);
}
__device__ inline unsigned int pkbf(float lo, float hi) {
  __hip_bfloat162 p = __float22bfloat162_rn(make_float2(lo, hi));
  unsigned int r;
  __builtin_memcpy(&r, &p, 4);
  return r;
}
__device__ inline float mish_f(float x) {
  if (x > 30.f) return x;
  float e = __expf(x);
  float u = 1.f + e;
  float u2 = u * u;
  return x * (u2 - 1.f) / (u2 + 1.f);
}
__device__ inline int swz(int row, int col) {
  return row * DIN + (col ^ ((row & 7) << 3));
}

// Stage a 32x128 bf16 tile into an 8KB LDS region via global_load_lds w=16,
// NTHR threads. LDS dest LINEAR (rule #21); XOR swizzle on the GLOBAL source.
__device__ inline void stage8k(const unsigned short* __restrict__ gsrc,
                               unsigned short* region, int tid) {
#pragma unroll
  for (int it = 0; it < 512 / NTHR; ++it) {
    int slot = it * NTHR + tid;      // 0..511
    int r = slot >> 4;               // 0..31
    int c8 = (slot & 15) ^ (r & 7);
    __builtin_amdgcn_global_load_lds((const as1u32*)(gsrc + r * DIN + c8 * 8),
                                     (as3u32*)(region + slot * 8), 16, 0, 0);
  }
}

// ---------- single fused precompute kernel (R15-proven) ----------

__global__ __launch_bounds__(256) void k_pre(
    const float* __restrict__ W1, const float* __restrict__ W2,
    const float* __restrict__ Wc, const float* __restrict__ Wa,
    const float* __restrict__ mlg, const float* __restrict__ b1,
    const float* __restrict__ b2,
    unsigned short* W1b, unsigned short* W2b, unsigned short* Wcb,
    unsigned short* ancb, float* a2) {
  const int blk = blockIdx.x;
  const int tid = threadIdx.x;
  if (blk < 192) {
    int i = blk * 256 + tid;  // 49152 total
    if (i < 16384) {
      W1b[i] = f2bf(W1[i]);
    } else if (i < 32768) {
      W2b[i - 16384] = f2bf(W2[i - 16384]);
    } else {
      int j = i - 32768;  // [16][1024] padded Wc (rows >= DOUT zero)
      int o = j >> 10;
      int s = j & 1023;
      Wcb[j] = (o < DOUT) ? f2bf(Wc[o * SSIZE + s]) : (unsigned short)0;
    }
    return;
  }
  __shared__ __align__(16) float AR[8][132];
  __shared__ __align__(16) float OUT[8][132];
  __shared__ __align__(16) float WC[32][132];
  const int s0 = (blk - 192) * 8;

  {
    const int d = tid & 127;
    const int sg = tid >> 7;
    float ac0 = 0.f, ac1 = 0.f, ac2 = 0.f, ac3 = 0.f;
    const float* wr = Wa + (size_t)(s0 + sg * 4) * MLGK;
    for (int k = 0; k < MLGK; ++k) {
      float m = mlg[k * DIN + d];
      ac0 = fmaf(wr[0 * MLGK + k], m, ac0);
      ac1 = fmaf(wr[1 * MLGK + k], m, ac1);
      ac2 = fmaf(wr[2 * MLGK + k], m, ac2);
      ac3 = fmaf(wr[3 * MLGK + k], m, ac3);
    }
    AR[sg * 4 + 0][d] = tanhf(ac0);
    AR[sg * 4 + 1][d] = tanhf(ac1);
    AR[sg * 4 + 2][d] = tanhf(ac2);
    AR[sg * 4 + 3][d] = tanhf(ac3);
  }
  __syncthreads();

  const int a = tid >> 5;
  const int c = tid & 31;
  float sqacc = 0.f;
#pragma unroll 1
  for (int layer = 0; layer < 2; ++layer) {
    const float* W = layer ? W2 : W1;
    const float* bias = layer ? b2 : b1;
#pragma unroll 1
    for (int ch = 0; ch < 4; ++ch) {
      for (int i = tid; i < 32 * 32; i += 256) {
        int cr = i >> 5;
        int g = i & 31;
        float4 v = *(const float4*)&W[(size_t)(ch * 32 + cr) * DIN + g * 4];
        *(float4*)&WC[cr][g * 4] = v;
      }
      __syncthreads();
      float acc = 0.f;
      const float* src = layer ? &OUT[a][0] : &AR[a][0];
#pragma unroll
      for (int g = 0; g < 32; ++g) {
        float4 av = *(const float4*)&src[g * 4];
        float4 wv = *(const float4*)&WC[c][g * 4];
        acc = fmaf(av.x, wv.x, acc);
        acc = fmaf(av.y, wv.y, acc);
        acc = fmaf(av.z, wv.z, acc);
        acc = fmaf(av.w, wv.w, acc);
      }
      int col = ch * 32 + c;
      float m = mish_f(acc + bias[col]);
      if (layer == 0) {
        OUT[a][col] = m;
      } else {
        unsigned short mb = f2bf(m);
        ancb[(size_t)(s0 + a) * DIN + col] = mb;
        float v = bf2f(mb);
        sqacc = fmaf(v, v, sqacc);
      }
      __syncthreads();
    }
  }
  sqacc += __shfl_xor(sqacc, 1);
  sqacc += __shfl_xor(sqacc, 2);
  sqacc += __shfl_xor(sqacc, 4);
  sqacc += __shfl_xor(sqacc, 8);
  sqacc += __shfl_xor(sqacc, 16);
  if (c == 0) a2[s0 + a] = sqacc;
}

// ---------- fused main kernel: TM=128, 4 waves x 32 rows ----------
// R17's proven per-wave shape (32 rows, ds:MFMA 1:2.25) with 2x waves/CU:
// grid 512 -> 2 blocks/CU x 8 waves = 16 waves/CU (~50% vs R17's 21%).
// LDS 40KB: reg0 = x_dml 128x128 (first 8KB reused as anchor buf A after
// the bx hoist), reg1 = 8KB W-quarter / anchor buf B. Numerics identical.

__global__ __launch_bounds__(NTHR, 2) void k_main(
    const float* __restrict__ x, const float* __restrict__ b1,
    const float* __restrict__ b2, const float* __restrict__ bc,
    const unsigned short* __restrict__ W1b, const unsigned short* __restrict__ W2b,
    const unsigned short* __restrict__ Wcb, const unsigned short* __restrict__ ancb,
    const float* __restrict__ a2, float* __restrict__ out) {
  __shared__ __align__(16) unsigned short reg0[TM * DIN];  // x_dml; anchor buf A (first 8KB)
  __shared__ __align__(16) unsigned short reg1[TS * DIN];  // W quarters; anchor buf B

  const int tid = threadIdx.x;
  const int lane = tid & 63;
  const int l15 = lane & 15;
  const int lhi = lane >> 4;
  const int n0 = blockIdx.x * TM;
  const int wbase = (tid >> 6) * 32;   // wave w -> rows [w*32, w*32+32)

  // issue first W quarter stage; x loads fly underneath
  stage8k(W1b, reg1, tid);

  // ---- x rows -> bf16 A-fragments (2 halves) ----
  short8 ah0[4], ah1[4];
#pragma unroll
  for (int h = 0; h < 2; ++h) {
#pragma unroll
    for (int kk = 0; kk < 4; ++kk) {
      const float* p = x + (size_t)(n0 + wbase + h * 16 + l15) * DIN + kk * 32 + lhi * 8;
      float4 u = *(const float4*)p;
      float4 v = *(const float4*)(p + 4);
      pk8 a;
      a.w[0] = pkbf(u.x, u.y);
      a.w[1] = pkbf(u.z, u.w);
      a.w[2] = pkbf(v.x, v.y);
      a.w[3] = pkbf(v.z, v.w);
      if (h == 0) ah0[kk] = a.s8; else ah1[kk] = a.s8;
    }
  }

  // ---- encode: 2 layers x 4 staged 32-col quarters of W ----
#pragma unroll 1
  for (int qq = 0; qq < 8; ++qq) {
    const int layer = qq >> 2;
    const int q = qq & 3;
    const float* bias = layer ? b2 : b1;
    if (q == 0 && layer == 1) {
      // reload A-fragments from h (own rows; wave-private, lgkmcnt-ordered)
#pragma unroll
      for (int kk = 0; kk < 4; ++kk) {
        ah0[kk] = *(const short8*)&reg0[swz(wbase + l15, kk * 32 + lhi * 8)];
        ah1[kk] = *(const short8*)&reg0[swz(wbase + 16 + l15, kk * 32 + lhi * 8)];
      }
    }
    __syncthreads();  // quarter qq staged (vmcnt drained by barrier)
    float4v e00 = (float4v){0.f, 0.f, 0.f, 0.f};  // (half0, ct0)
    float4v e10 = (float4v){0.f, 0.f, 0.f, 0.f};  // (half0, ct1)
    float4v e01 = (float4v){0.f, 0.f, 0.f, 0.f};  // (half1, ct0)
    float4v e11 = (float4v){0.f, 0.f, 0.f, 0.f};  // (half1, ct1)
#pragma unroll
    for (int kk = 0; kk < 4; ++kk) {
      int k = kk * 32 + lhi * 8;
      short8 w0 = *(const short8*)&reg1[swz(l15, k)];
      short8 w1 = *(const short8*)&reg1[swz(16 + l15, k)];
      e00 = __builtin_amdgcn_mfma_f32_16x16x32_bf16(ah0[kk], w0, e00, 0, 0, 0);
      e10 = __builtin_amdgcn_mfma_f32_16x16x32_bf16(ah0[kk], w1, e10, 0, 0, 0);
      e01 = __builtin_amdgcn_mfma_f32_16x16x32_bf16(ah1[kk], w0, e01, 0, 0, 0);
      e11 = __builtin_amdgcn_mfma_f32_16x16x32_bf16(ah1[kk], w1, e11, 0, 0, 0);
    }
    __syncthreads();  // all waves done reading reg1
    if (qq < 7) {
      const unsigned short* Wn = (qq + 1 < 4) ? W1b + (size_t)((qq + 1) * 32) * DIN
                                              : W2b + (size_t)(((qq + 1) & 3) * 32) * DIN;
      stage8k(Wn, reg1, tid);
    }
#pragma unroll
    for (int h = 0; h < 2; ++h) {
#pragma unroll
      for (int ct = 0; ct < 2; ++ct) {
        float4v accv = (h == 0) ? (ct ? e10 : e00) : (ct ? e11 : e01);
        int col = q * 32 + ct * 16 + l15;
        float bv = bias[col];
        float m0 = mish_f(accv[0] + bv);
        float m1 = mish_f(accv[1] + bv);
        float m2 = mish_f(accv[2] + bv);
        float m3 = mish_f(accv[3] + bv);
        unsigned int w01 = pkbf(m0, m1);
        unsigned int w23 = pkbf(m2, m3);
        int r0 = wbase + h * 16 + lhi * 4;
        reg0[swz(r0 + 0, col)] = (unsigned short)(w01 & 0xffff);
        reg0[swz(r0 + 1, col)] = (unsigned short)(w01 >> 16);
        reg0[swz(r0 + 2, col)] = (unsigned short)(w23 & 0xffff);
        reg0[swz(r0 + 3, col)] = (unsigned short)(w23 >> 16);
      }
    }
  }

  // ---- hoist x_dml B-fragments (both halves) + row norms ----
  short8 bx0[4], bx1[4];
#pragma unroll
  for (int kk = 0; kk < 4; ++kk) {
    bx0[kk] = *(const short8*)&reg0[swz(wbase + l15, kk * 32 + lhi * 8)];
    bx1[kk] = *(const short8*)&reg0[swz(wbase + 16 + l15, kk * 32 + lhi * 8)];
  }
  float x2v0 = 0.f, x2v1 = 0.f;
#pragma unroll
  for (int kk = 0; kk < 4; ++kk)
#pragma unroll
    for (int e = 0; e < 8; ++e) {
      float v0 = bf2f((unsigned short)bx0[kk][e]);
      float v1 = bf2f((unsigned short)bx1[kk][e]);
      x2v0 = fmaf(v0, v0, x2v0);
      x2v1 = fmaf(v1, v1, x2v1);
    }
  x2v0 += __shfl_xor(x2v0, 16); x2v0 += __shfl_xor(x2v0, 32);
  x2v1 += __shfl_xor(x2v1, 16); x2v1 += __shfl_xor(x2v1, 32);

  // ---- prefetch tile 0's a2 / Wc (named scalars, shared by both halves) ----
  const unsigned short* wcrow = Wcb + l15 * SSIZE;
  float4 av0 = *(const float4*)(a2 + lhi * 4);
  float4 av1 = *(const float4*)(a2 + 16 + lhi * 4);
  uint2 wv0 = *(const uint2*)(wcrow + lhi * 4);
  uint2 wv1 = *(const uint2*)(wcrow + 16 + lhi * 4);
  __syncthreads();              // everyone hoisted before anchor staging

  // ---- distance + in-register logits over 32 anchor tiles of 32 ----
  float4v lacc0 = (float4v){0.f, 0.f, 0.f, 0.f};
  float4v lacc1 = (float4v){0.f, 0.f, 0.f, 0.f};

  auto dist_tile = [&](const unsigned short* buf, int t) {
    int tn = (t + 1) & (NT - 1);
    const float* a2n = a2 + tn * TS + lhi * 4;
    const unsigned short* wcn = wcrow + tn * TS + lhi * 4;
    float4 an0 = *(const float4*)(a2n + 0);
    float4 an1 = *(const float4*)(a2n + 16);
    uint2 wn0 = *(const uint2*)(wcn + 0);
    uint2 wn1 = *(const uint2*)(wcn + 16);

    float4v a00 = (float4v){0.f, 0.f, 0.f, 0.f};  // (ct0, half0)
    float4v a01 = (float4v){0.f, 0.f, 0.f, 0.f};  // (ct0, half1)
    float4v a10 = (float4v){0.f, 0.f, 0.f, 0.f};  // (ct1, half0)
    float4v a11 = (float4v){0.f, 0.f, 0.f, 0.f};  // (ct1, half1)
    __builtin_amdgcn_s_setprio(1);
#pragma unroll
    for (int kk = 0; kk < 4; ++kk) {
      int k = kk * 32 + lhi * 8;
      short8 f0 = *(const short8*)&buf[swz(l15, k)];       // anchors ct0
      short8 f1 = *(const short8*)&buf[swz(16 + l15, k)];  // anchors ct1
      a00 = __builtin_amdgcn_mfma_f32_16x16x32_bf16(f0, bx0[kk], a00, 0, 0, 0);
      a01 = __builtin_amdgcn_mfma_f32_16x16x32_bf16(f0, bx1[kk], a01, 0, 0, 0);
      a10 = __builtin_amdgcn_mfma_f32_16x16x32_bf16(f1, bx0[kk], a10, 0, 0, 0);
      a11 = __builtin_amdgcn_mfma_f32_16x16x32_bf16(f1, bx1[kk], a11, 0, 0, 0);
    }
    __builtin_amdgcn_s_setprio(0);
    // epilogue half 0 (rows wbase+l15)
    {
      pk8 A, B;
      float d0 = fsqrt_fast(fmaxf(fmaf(-2.f, a00[0], x2v0 + av0.x), 0.f));
      float d1 = fsqrt_fast(fmaxf(fmaf(-2.f, a00[1], x2v0 + av0.y), 0.f));
      float d2 = fsqrt_fast(fmaxf(fmaf(-2.f, a00[2], x2v0 + av0.z), 0.f));
      float d3 = fsqrt_fast(fmaxf(fmaf(-2.f, a00[3], x2v0 + av0.w), 0.f));
      A.w[0] = wv0.x; A.w[1] = wv0.y;
      B.w[0] = pkbf(d0, d1); B.w[1] = pkbf(d2, d3);
      float e0 = fsqrt_fast(fmaxf(fmaf(-2.f, a10[0], x2v0 + av1.x), 0.f));
      float e1 = fsqrt_fast(fmaxf(fmaf(-2.f, a10[1], x2v0 + av1.y), 0.f));
      float e2 = fsqrt_fast(fmaxf(fmaf(-2.f, a10[2], x2v0 + av1.z), 0.f));
      float e3 = fsqrt_fast(fmaxf(fmaf(-2.f, a10[3], x2v0 + av1.w), 0.f));
      A.w[2] = wv1.x; A.w[3] = wv1.y;
      B.w[2] = pkbf(e0, e1); B.w[3] = pkbf(e2, e3);
      lacc0 = __builtin_amdgcn_mfma_f32_16x16x32_bf16(A.s8, B.s8, lacc0, 0, 0, 0);
    }
    // epilogue half 1 (rows wbase+16+l15)
    {
      pk8 A, B;
      float d0 = fsqrt_fast(fmaxf(fmaf(-2.f, a01[0], x2v1 + av0.x), 0.f));
      float d1 = fsqrt_fast(fmaxf(fmaf(-2.f, a01[1], x2v1 + av0.y), 0.f));
      float d2 = fsqrt_fast(fmaxf(fmaf(-2.f, a01[2], x2v1 + av0.z), 0.f));
      float d3 = fsqrt_fast(fmaxf(fmaf(-2.f, a01[3], x2v1 + av0.w), 0.f));
      A.w[0] = wv0.x; A.w[1] = wv0.y;
      B.w[0] = pkbf(d0, d1); B.w[1] = pkbf(d2, d3);
      float e0 = fsqrt_fast(fmaxf(fmaf(-2.f, a11[0], x2v1 + av1.x), 0.f));
      float e1 = fsqrt_fast(fmaxf(fmaf(-2.f, a11[1], x2v1 + av1.y), 0.f));
      float e2 = fsqrt_fast(fmaxf(fmaf(-2.f, a11[2], x2v1 + av1.z), 0.f));
      float e3 = fsqrt_fast(fmaxf(fmaf(-2.f, a11[3], x2v1 + av1.w), 0.f));
      A.w[2] = wv1.x; A.w[3] = wv1.y;
      B.w[2] = pkbf(e0, e1); B.w[3] = pkbf(e2, e3);
      lacc1 = __builtin_amdgcn_mfma_f32_16x16x32_bf16(A.s8, B.s8, lacc1, 0, 0, 0);
    }
    av0 = an0; av1 = an1; wv0 = wn0; wv1 = wn1;
  };

  stage8k(ancb, reg0, tid);  // tile 0 -> buf A (first 8KB of reg0)
  __syncthreads();
#pragma unroll 1
  for (int tp = 0; tp < NT / 2; ++tp) {
    stage8k(ancb + (size_t)(2 * tp + 1) * TS * DIN, reg1, tid);
    dist_tile(reg0, 2 * tp);
    __syncthreads();
    if (tp < NT / 2 - 1)
      stage8k(ancb + (size_t)(2 * tp + 2) * TS * DIN, reg0, tid);
    dist_tile(reg1, 2 * tp + 1);
    __syncthreads();
  }

  // ---- bias + log_softmax + store, per row-half ----
#pragma unroll
  for (int h = 0; h < 2; ++h) {
    float4v L = h ? lacc1 : lacc0;
    const int xrow = n0 + wbase + h * 16 + l15;
    float v[4];
    float m4 = -1e30f;
#pragma unroll
    for (int j = 0; j < 4; ++j) {
      int o = lhi * 4 + j;
      v[j] = (o < DOUT) ? (L[j] + bc[o]) : -1e30f;
      m4 = fmaxf(m4, v[j]);
    }
    m4 = fmaxf(m4, __shfl_xor(m4, 16));
    m4 = fmaxf(m4, __shfl_xor(m4, 32));
    float es = 0.f;
#pragma unroll
    for (int j = 0; j < 4; ++j) {
      int o = lhi * 4 + j;
      es += (o < DOUT) ? __expf(v[j] - m4) : 0.f;
    }
    es += __shfl_xor(es, 16);
    es += __shfl_xor(es, 32);
    float ls = logf(es);
#pragma unroll
    for (int j = 0; j < 4; ++j) {
      int o = lhi * 4 + j;
      if (o < DOUT) out[(size_t)xrow * DOUT + o] = v[j] - m4 - ls;
    }
  }
}

extern "C" void kernel_launch(void* const* d_in, const int* in_sizes, int n_in,
                              void* d_out, int out_size, void* d_ws, size_t ws_size,
                              hipStream_t stream) {
  const float* x   = (const float*)d_in[0];
  const float* mlg = (const float*)d_in[1];
  const float* W1  = (const float*)d_in[2];
  const float* b1  = (const float*)d_in[3];
  const float* W2  = (const float*)d_in[4];
  const float* b2  = (const float*)d_in[5];
  const float* Wa  = (const float*)d_in[6];
  const float* Wc  = (const float*)d_in[7];
  const float* bc  = (const float*)d_in[8];
  float* out = (float*)d_out;

  // workspace layout (~0.36 MB)
  unsigned short* W1b  = (unsigned short*)d_ws;        // 16384 bf16
  unsigned short* W2b  = W1b + 16384;                  // 16384 bf16
  unsigned short* Wcb  = W2b + 16384;                  // 16*1024 bf16 (zero-padded)
  unsigned short* ancb = Wcb + 16384;                  // 1024*128 bf16
  float* a2 = (float*)(ancb + SSIZE * DIN);            // 1024 f32

  k_pre<<<320, 256, 0, stream>>>(W1, W2, Wc, Wa, mlg, b1, b2,
                                 W1b, W2b, Wcb, ancb, a2);
  k_main<<<512, NTHR, 0, stream>>>(x, b1, b2, bc, W1b, W2b, Wcb, ancb, a2, out);
}